// Round 11
// baseline (339.961 us; speedup 1.0000x reference)
//
#include <hip/hip_runtime.h>

#define NN 100000
#define NE 3200000
#define NB 391          // buckets of 256 nodes
#define CAP 9216        // fixed per-bucket capacity (mean 8192, sigma ~90 -> 11-sigma)
#define CHUNK 6250      // edges per sorter block (512 x 6250 = NE exactly)
#define NSBLK 512
#define LN_EPS 1e-5f

__device__ __forceinline__ unsigned short f2bf(float f) {   // RNE f32 -> bf16
  unsigned b = __float_as_uint(f);
  b += 0x7FFF + ((b >> 16) & 1);
  return (unsigned short)(b >> 16);
}
__device__ __forceinline__ float bflo(unsigned u) { return __uint_as_float(u << 16); }
__device__ __forceinline__ float bfhi(unsigned u) { return __uint_as_float(u & 0xFFFF0000u); }

// ---------------- init per-bucket cursors ----------------

__global__ __launch_bounds__(256) void k_init(int* __restrict__ bcur) {
  int i = blockIdx.x * 256 + threadIdx.x;
  if (i < NB) bcur[i] = i * CAP;
}

// ---------------- bucket sort: block-local counting sort, contiguous run writes ----------------

__global__ __launch_bounds__(256) void k_bucket(const int* __restrict__ src, const int* __restrict__ dst,
                                                int* __restrict__ bcur, unsigned* __restrict__ packed) {
  __shared__ int lh[NB];        // counts, then rank counters
  __shared__ int lstart[NB];    // local exclusive scan
  __shared__ int lg[NB];        // reserved global base per bucket
  __shared__ int sc[512];       // scan temp
  __shared__ unsigned buf[CHUNK];
  int tid = threadIdx.x;
  for (int i = tid; i < NB; i += 256) lh[i] = 0;
  __syncthreads();
  int base = blockIdx.x * CHUNK;
  // pass 1: local histogram; cache src/dst in registers
  int dreg[25], sreg[25];
  #pragma unroll
  for (int k = 0; k < 25; ++k) {
    int idx = tid + k * 256;
    int e = base + idx;
    bool v = (idx < CHUNK) && (e < NE);
    dreg[k] = v ? dst[e] : -1;
    sreg[k] = v ? src[e] : 0;
    if (v) atomicAdd(&lh[dreg[k] >> 8], 1);
  }
  __syncthreads();
  // local exclusive scan (512-wide Hillis-Steele, 2 slots/thread)
  int ia = tid, ib = tid + 256;
  sc[ia] = (ia < NB) ? lh[ia] : 0;
  sc[ib] = (ib < NB) ? lh[ib] : 0;
  __syncthreads();
  for (int off = 1; off < 512; off <<= 1) {
    int va = (ia >= off) ? sc[ia - off] : 0;
    int vb = (ib >= off) ? sc[ib - off] : 0;
    __syncthreads();
    sc[ia] += va;
    sc[ib] += vb;
    __syncthreads();
  }
  if (ia < NB) lstart[ia] = sc[ia] - lh[ia];
  if (ib < NB) lstart[ib] = sc[ib] - lh[ib];
  // reserve global space per bucket (bcur pre-initialized to b*CAP)
  for (int i = tid; i < NB; i += 256) {
    int c = lh[i];
    lg[i] = c ? atomicAdd(&bcur[i], c) : 0;
  }
  __syncthreads();
  for (int i = tid; i < NB; i += 256) lh[i] = 0;   // reset as rank counters
  __syncthreads();
  // pass 2: rank + reorder into LDS (register-cached src/dst)
  #pragma unroll
  for (int k = 0; k < 25; ++k) {
    int d = dreg[k];
    if (d >= 0) {
      int b = d >> 8;
      int r = atomicAdd(&lh[b], 1);
      buf[lstart[b] + r] = (unsigned)sreg[k] | ((unsigned)(d & 255) << 24);
    }
  }
  __syncthreads();
  // output: half-wave per bucket run -> contiguous writes
  int hw = tid >> 5, l = tid & 31;
  for (int b = hw; b < NB; b += 8) {
    int cnt = lh[b], st = lstart[b], gp = lg[b];
    for (int j = l; j < cnt; j += 32) packed[gp + j] = buf[st + j];
  }
}

// ------- per-bucket node sort: packed -> per-node CSR + noff/ncnt + ds -------

__global__ __launch_bounds__(256) void k_nodesort(const unsigned* __restrict__ packed,
                                                  const int* __restrict__ bcur,
                                                  int* __restrict__ csr, int* __restrict__ noff,
                                                  int* __restrict__ ncnt, float* __restrict__ ds) {
  __shared__ int h[256], lstart[256], cur[256], sc[256];
  int tid = threadIdx.x;
  h[tid] = 0;
  __syncthreads();
  int b = blockIdx.x;
  int o = b * CAP, e1 = bcur[b];
  for (int i = o + tid; i < e1; i += 256) atomicAdd(&h[packed[i] >> 24], 1);
  __syncthreads();
  int c = h[tid];
  sc[tid] = c;
  __syncthreads();
  for (int off = 1; off < 256; off <<= 1) {
    int v = (tid >= off) ? sc[tid - off] : 0;
    __syncthreads();
    sc[tid] += v;
    __syncthreads();
  }
  int ex = sc[tid] - c;
  lstart[tid] = ex;
  cur[tid] = 0;
  int n = b * 256 + tid;
  if (n < NN) {
    noff[n] = o + ex;
    ncnt[n] = c;
    ds[n] = rsqrtf((float)c + 1.0f);
  }
  __syncthreads();
  for (int i = o + tid; i < e1; i += 256) {
    unsigned e = packed[i];
    int dl = e >> 24;
    int r = atomicAdd(&cur[dl], 1);
    csr[o + lstart[dl] + r] = (int)(e & 0xFFFFFF);
  }
}

// ---------------- GEMM1: xw1h = bf16((x @ W1) * ds)  (128 -> 32) ----------------

__global__ __launch_bounds__(256) void k_gemm1(const float* __restrict__ x, const float* __restrict__ W1,
                                               const float* __restrict__ ds,
                                               unsigned short* __restrict__ xw1h) {
  __shared__ float Wt[32][132];
  __shared__ float xr[8][128];
  for (int idx = threadIdx.x; idx < 4096; idx += 256) {
    int k = idx >> 5, c = idx & 31;
    Wt[c][k] = W1[idx];
  }
  __syncthreads();
  int g = threadIdx.x >> 5, lane = threadIdx.x & 31;
  for (int tile = blockIdx.x; tile < NN / 8; tile += gridDim.x) {
    int row = tile * 8 + g;
    float4 xv = *(const float4*)&x[row * 128 + lane * 4];
    *(float4*)&xr[g][lane * 4] = xv;                  // group-private: same-wave LDS, no block barrier
    __builtin_amdgcn_wave_barrier();
    float acc = 0.f;
    #pragma unroll
    for (int k4 = 0; k4 < 32; ++k4) {
      float4 a = *(const float4*)&xr[g][k4 * 4];
      float4 b = *(const float4*)&Wt[lane][k4 * 4];
      acc = fmaf(a.x, b.x, acc);
      acc = fmaf(a.y, b.y, acc);
      acc = fmaf(a.z, b.z, acc);
      acc = fmaf(a.w, b.w, acc);
    }
    xw1h[row * 32 + lane] = f2bf(acc * ds[row]);
    __builtin_amdgcn_wave_barrier();                  // keep next tile's write below these reads
  }
}

// ------- per-node gather: 4-lane groups x uint4 (16 rows in flight / wave-instr),
//         LDS transpose, 32-lane LN + ReLU + @Wnext epilogue -------

#define ACC8(U) { a0 += bflo(U.x); a1 += bfhi(U.x); a2 += bflo(U.y); a3 += bfhi(U.y); \
                  a4 += bflo(U.z); a5 += bfhi(U.z); a6 += bflo(U.w); a7 += bfhi(U.w); }

template <int NOUT>
__global__ __launch_bounds__(256, 4) void k_csragg(const unsigned* __restrict__ xwsh, const int* __restrict__ csr,
    const int* __restrict__ noff, const int* __restrict__ ncnt, const float* __restrict__ ds,
    const float* __restrict__ bias, const float* __restrict__ gam, const float* __restrict__ bet,
    const float* __restrict__ Wn, void* __restrict__ outp) {
  __shared__ float Wl[1024];
  __shared__ float accL[64 * 33];     // [node][ch], stride 33 -> max 2-way bank alias (free)
  int tid = threadIdx.x;
  if (NOUT == 32) {
    for (int i = tid; i < 1024; i += 256) Wl[i] = Wn[i];
  }
  int g4 = tid >> 2, l4 = tid & 3;    // 64 groups of 4 lanes; lane owns channels 8*l4..8*l4+7
  int nb = blockIdx.x * 64;           // grid: ceil(NN/64) = 1563
  int n0 = nb + g4;
  bool valid = n0 < NN;
  int o = valid ? noff[n0] : 0;
  int cnt = valid ? ncnt[n0] : 0;
  const uint4* xw4 = (const uint4*)xwsh;
  float a0 = 0.f, a1 = 0.f, a2 = 0.f, a3 = 0.f, a4 = 0.f, a5 = 0.f, a6 = 0.f, a7 = 0.f;
  int i = o, end = o + cnt;
  for (; i + 8 <= end; i += 8) {      // 8 rows in flight per group; 16 groups/wave -> 128 lines/wave
    int s0 = csr[i],     s1 = csr[i + 1], s2 = csr[i + 2], s3 = csr[i + 3];
    int s4 = csr[i + 4], s5 = csr[i + 5], s6 = csr[i + 6], s7 = csr[i + 7];
    uint4 u0 = xw4[s0 * 4 + l4];
    uint4 u1 = xw4[s1 * 4 + l4];
    uint4 u2 = xw4[s2 * 4 + l4];
    uint4 u3 = xw4[s3 * 4 + l4];
    uint4 u4 = xw4[s4 * 4 + l4];
    uint4 u5 = xw4[s5 * 4 + l4];
    uint4 u6 = xw4[s6 * 4 + l4];
    uint4 u7 = xw4[s7 * 4 + l4];
    ACC8(u0); ACC8(u1); ACC8(u2); ACC8(u3);
    ACC8(u4); ACC8(u5); ACC8(u6); ACC8(u7);
  }
  for (; i < end; ++i) {
    uint4 u = xw4[csr[i] * 4 + l4];
    ACC8(u);
  }
  {
    int base = g4 * 33 + l4 * 8;
    accL[base]     = a0; accL[base + 1] = a1; accL[base + 2] = a2; accL[base + 3] = a3;
    accL[base + 4] = a4; accL[base + 5] = a5; accL[base + 6] = a6; accL[base + 7] = a7;
  }
  __syncthreads();
  // epilogue: 8 half-waves x 32 lanes, lane = channel (round-6 proven structure)
  int hw = tid >> 5, l = tid & 31;
  for (int dl = hw; dl < 64; dl += 8) {
    int n = nb + dl;
    if (n >= NN) break;
    float aggv = accL[dl * 33 + l];
    float dsn = ds[n];
    unsigned us = xwsh[n * 16 + (l >> 1)];
    float sv = (l & 1) ? bfhi(us) : bflo(us);
    float val = dsn * (aggv + sv) + bias[l];
    float sum = val;
    #pragma unroll
    for (int o2 = 16; o2 > 0; o2 >>= 1) sum += __shfl_xor(sum, o2, 32);
    float mu = sum * (1.f / 32.f);
    float d = val - mu;
    float sq = d * d;
    #pragma unroll
    for (int o2 = 16; o2 > 0; o2 >>= 1) sq += __shfl_xor(sq, o2, 32);
    float h = d * rsqrtf(sq * (1.f / 32.f) + LN_EPS) * gam[l] + bet[l];
    h = fmaxf(h, 0.f);   // ReLU (dropout = identity in eval)
    if (NOUT == 32) {
      float a9 = 0.f;
      #pragma unroll
      for (int c = 0; c < 32; ++c) {
        float hc = __shfl(h, c, 32);
        a9 = fmaf(hc, Wl[c * 32 + l], a9);
      }
      unsigned mybf = (unsigned)f2bf(a9 * dsn);
      unsigned nxt = __shfl_down(mybf, 1, 32);
      if (!(l & 1)) ((unsigned*)outp)[n * 16 + (l >> 1)] = mybf | (nxt << 16);
    } else {
      float2 wv = ((const float2*)Wn)[l];   // row l of W3[32][2]
      float p0 = h * wv.x;
      float p1 = h * wv.y;
      #pragma unroll
      for (int o2 = 16; o2 > 0; o2 >>= 1) { p0 += __shfl_xor(p0, o2, 32); p1 += __shfl_xor(p1, o2, 32); }
      if (l == 0) {
        float2 r = {p0 * dsn, p1 * dsn};
        *(float2*)&((float*)outp)[n * 2] = r;
      }
    }
  }
}

// ---------------- final aggregation (2 channels, f32) -> logits ----------------

__global__ __launch_bounds__(256) void k_fin2(const float* __restrict__ xws, const int* __restrict__ csr,
    const int* __restrict__ noff, const int* __restrict__ ncnt, const float* __restrict__ ds,
    const float* __restrict__ b3, float* __restrict__ out) {
  int tid = threadIdx.x;
  int hw = tid >> 5, l = tid & 31;
  int n = blockIdx.x * 8 + hw;
  int o = noff[n], end = o + ncnt[n];
  float a0 = 0.f, a1 = 0.f;
  for (int i = o + l; i < end; i += 32) {
    int s = csr[i];
    float2 v = *(const float2*)&xws[s * 2];
    a0 += v.x; a1 += v.y;
  }
  for (int o2 = 16; o2 > 0; o2 >>= 1) { a0 += __shfl_xor(a0, o2, 32); a1 += __shfl_xor(a1, o2, 32); }
  if (l == 0) {
    float dsn = ds[n];
    float2 sv = *(const float2*)&xws[n * 2];
    out[n * 2]     = dsn * (a0 + sv.x) + b3[0];
    out[n * 2 + 1] = dsn * (a1 + sv.y) + b3[1];
  }
}

extern "C" void kernel_launch(void* const* d_in, const int* in_sizes, int n_in,
                              void* d_out, int out_size, void* d_ws, size_t ws_size,
                              hipStream_t stream) {
  (void)in_sizes; (void)n_in; (void)out_size; (void)ws_size;
  const float* x   = (const float*)d_in[0];
  const int*   ei  = (const int*)d_in[1];
  const float* W1  = (const float*)d_in[2];
  const float* b1  = (const float*)d_in[3];
  const float* g1  = (const float*)d_in[4];
  const float* be1 = (const float*)d_in[5];
  const float* W2  = (const float*)d_in[6];
  const float* b2  = (const float*)d_in[7];
  const float* g2  = (const float*)d_in[8];
  const float* be2 = (const float*)d_in[9];
  const float* W3  = (const float*)d_in[10];
  const float* b3  = (const float*)d_in[11];
  const int* src = ei;
  const int* dst = ei + NE;
  float* out = (float*)d_out;

  char* w = (char*)d_ws;
  int*      bcur   = (int*)(w);                        // 1.6 KB
  int*      noff   = (int*)(w + (64u << 10));          // 400 KB
  int*      ncnt   = (int*)(w + (512u << 10));         // 400 KB
  float*    ds     = (float*)(w + (1024u << 10));      // 400 KB
  unsigned* packed = (unsigned*)(w + (2u << 20));      // 14.42 MB (dead after k_nodesort)
  int*      csr    = (int*)(w + (17u << 20));          // 14.42 MB (ends 31.4M)
  unsigned short* xw1h = (unsigned short*)(w + (2u << 20));   // bf16 6.4 MB, overlays dead packed
  float*    xw3s   = (float*)(w + (10u << 20));        // f32 0.8 MB (past xw1h, inside old packed)
  unsigned short* xw2h = (unsigned short*)(w + (32u << 20));  // bf16 6.4 MB (ends 38.4M)

  k_init    <<<2,     256, 0, stream>>>(bcur);
  k_bucket  <<<NSBLK, 256, 0, stream>>>(src, dst, bcur, packed);
  k_nodesort<<<NB,    256, 0, stream>>>(packed, bcur, csr, noff, ncnt, ds);
  k_gemm1   <<<2048,  256, 0, stream>>>(x, W1, ds, xw1h);
  k_csragg<32><<<1563, 256, 0, stream>>>((const unsigned*)xw1h, csr, noff, ncnt, ds, b1, g1, be1, W2, xw2h);
  k_csragg<2> <<<1563, 256, 0, stream>>>((const unsigned*)xw2h, csr, noff, ncnt, ds, b2, g2, be2, W3, xw3s);
  k_fin2    <<<NN/8,  256, 0, stream>>>(xw3s, csr, noff, ncnt, ds, b3, out);
}